// Round 10
// baseline (924.879 us; speedup 1.0000x reference)
//
#include <hip/hip_runtime.h>
#include <math.h>

#define C 256
#define S 16
#define CR 64
#define NREP 16        // psum replicas (atomic contention /16)

typedef float f4 __attribute__((ext_vector_type(4)));

// ---------------- Kernel 0: histogram of idx (counts per segment) ------------
__global__ __launch_bounds__(256) void k_hist(
    const int* __restrict__ idx, int* __restrict__ pcnt, int nrows)
{
    const int lane = threadIdx.x & 63;
    const int tid  = blockIdx.x * blockDim.x + threadIdx.x;
    const int T    = gridDim.x * blockDim.x;
    const int padded = ((nrows + 63) >> 6) << 6;

    int c0=0,c1=0,c2=0,c3=0,c4=0,c5=0,c6=0,c7=0,
        c8=0,c9=0,c10=0,c11=0,c12=0,c13=0,c14=0,c15=0;

    for (int i = tid; i < padded; i += T) {
        const int v = (i < nrows) ? idx[i] : -1;
        #define CNT(K) c##K += (int)__popcll(__ballot(v == K));
        CNT(0)  CNT(1)  CNT(2)  CNT(3)  CNT(4)  CNT(5)  CNT(6)  CNT(7)
        CNT(8)  CNT(9)  CNT(10) CNT(11) CNT(12) CNT(13) CNT(14) CNT(15)
        #undef CNT
    }
    if (lane == 0) {
        #define FL(K) if (c##K) atomicAdd(&pcnt[K], c##K);
        FL(0)  FL(1)  FL(2)  FL(3)  FL(4)  FL(5)  FL(6)  FL(7)
        FL(8)  FL(9)  FL(10) FL(11) FL(12) FL(13) FL(14) FL(15)
        #undef FL
    }
}

// ---------------- Kernel 0b: counting-sort scatter of row ids ----------------
// Groups row indices by segment into perm[] (within-segment order arbitrary).
// Per 2048-row chunk: LDS histogram -> one global reserve per segment ->
// LDS-atomic dense ranks -> scattered 4B writes of row ids.
__global__ __launch_bounds__(256) void k_scatter(
    const int* __restrict__ idx, const int* __restrict__ pcnt,
    int* __restrict__ cursor, int* __restrict__ perm, int nrows)
{
    __shared__ int lc[S];
    __shared__ int lb[S];
    const int t = threadIdx.x;

    // exclusive prefix of pcnt for thread t < 16
    int soff_t = 0;
    if (t < S) for (int j = 0; j < t; j++) soff_t += pcnt[j];

    const int nchunks = (nrows + 2047) >> 11;
    for (int c = blockIdx.x; c < nchunks; c += gridDim.x) {
        const int c0 = c << 11;
        const int c1 = min(c0 + 2048, nrows);
        if (t < S) lc[t] = 0;
        __syncthreads();
        for (int r = c0 + t; r < c1; r += 256) atomicAdd(&lc[idx[r]], 1);
        __syncthreads();
        if (t < S) lb[t] = soff_t + atomicAdd(&cursor[t], lc[t]);
        __syncthreads();
        for (int r = c0 + t; r < c1; r += 256) {
            const int pos = atomicAdd(&lb[idx[r]], 1);
            perm[pos] = r;
        }
        __syncthreads();
    }
}

// ---------------- Kernel 1: segment sums over perm — uniform, 4 VALU/16B -----
// Wave processes 256 contiguous perm entries (4 groups of 64). Segment is
// POSITIONAL (prefix-offset compare, wave-uniform scalar) -> single f4
// accumulator, flush only at segment boundaries. Hot loop: readlane row id,
// 8 independent 1KB-row loads, 32 v_add per 8 rows. No idx, no predication.
__global__ __launch_bounds__(256) void k_segsum(
    const float* __restrict__ x, const int* __restrict__ perm,
    const int* __restrict__ pcnt, float* __restrict__ psum, int nrows)
{
    const int lane = threadIdx.x & 63;
    const int wid  = (blockIdx.x * blockDim.x + threadIdx.x) >> 6;
    const int rep  = wid & (NREP - 1);
    float* gs = psum + (size_t)rep * S * C;

    // lane t holds soff[t] = sum_{j<t} pcnt[j]  (lane 16 = total)
    int soff_mine = 0;
    #pragma unroll
    for (int j = 0; j < S; j++) soff_mine += (lane > j) ? pcnt[j] : 0;
    #define SOFF(k) __shfl(soff_mine, (k))

    const f4* __restrict__ x4 = reinterpret_cast<const f4*>(x);
    const int w0 = wid << 8;                    // 256 rows per wave
    if (w0 >= nrows) return;

    f4  acc = {0, 0, 0, 0};
    int cur = 0;

    #define FLUSH() { float* fp = gs + cur * C + 4 * lane; \
        atomicAdd(fp + 0, acc.x); atomicAdd(fp + 1, acc.y); \
        atomicAdd(fp + 2, acc.z); atomicAdd(fp + 3, acc.w); \
        acc.x = 0; acc.y = 0; acc.z = 0; acc.w = 0; }

    #pragma unroll 1
    for (int g = 0; g < 4; g++) {
        const int jb = w0 + (g << 6);
        if (jb >= nrows) break;
        const int pv = perm[jb + lane];         // 64 row ids, coalesced
        while (jb >= SOFF(cur + 1)) { FLUSH() cur++; }     // advance (uniform)
        if (jb + 64 <= SOFF(cur + 1)) {
            // fast path: whole group in segment `cur`
            #pragma unroll
            for (int b = 0; b < 8; b++) {
                #define RL(K) const int r##K = __builtin_amdgcn_readlane(pv, b * 8 + K);
                RL(0) RL(1) RL(2) RL(3) RL(4) RL(5) RL(6) RL(7)
                #undef RL
                const f4 v0 = x4[(size_t)r0 * 64 + lane];
                const f4 v1 = x4[(size_t)r1 * 64 + lane];
                const f4 v2 = x4[(size_t)r2 * 64 + lane];
                const f4 v3 = x4[(size_t)r3 * 64 + lane];
                const f4 v4 = x4[(size_t)r4 * 64 + lane];
                const f4 v5 = x4[(size_t)r5 * 64 + lane];
                const f4 v6 = x4[(size_t)r6 * 64 + lane];
                const f4 v7 = x4[(size_t)r7 * 64 + lane];
                acc += ((v0 + v1) + (v2 + v3)) + ((v4 + v5) + (v6 + v7));
            }
        } else {
            // slow path: group spans a segment boundary (rare)
            for (int j = jb; j < jb + 64 && j < nrows; j++) {
                while (j >= SOFF(cur + 1)) { FLUSH() cur++; }
                const int row = __shfl(pv, j - jb);
                acc += x4[(size_t)row * 64 + lane];
            }
        }
    }
    FLUSH()
    #undef FLUSH
    #undef SOFF
}

// ---------------- Kernel 2: reduce replicas + tiny SE MLP ----------------
__global__ __launch_bounds__(256) void k_mlp(
    const float* __restrict__ psum, const int* __restrict__ pcnt,
    const float* __restrict__ w1, const float* __restrict__ w2,
    float* __restrict__ gate)
{
    __shared__ float sm[S][C];
    __shared__ float h[S][CR];
    __shared__ float cnt[S];
    const int t = threadIdx.x;

    if (t < S) cnt[t] = fmaxf((float)pcnt[t], 1.0f);
    __syncthreads();

    for (int i = t; i < S * C; i += 256) {
        float v = 0.0f;
        #pragma unroll
        for (int r = 0; r < NREP; r++) v += psum[r * S * C + i];
        sm[i / C][i % C] = v / cnt[i / C];
    }
    __syncthreads();

    for (int o = t; o < S * CR; o += 256) {
        const int s = o / CR, j = o % CR;
        float acc = 0.0f;
        #pragma unroll 4
        for (int k = 0; k < C; k++) acc += sm[s][k] * w1[k * CR + j];
        h[s][j] = fmaxf(acc, 0.0f);
    }
    __syncthreads();

    for (int o = t; o < S * C; o += 256) {
        const int s = o / C, j = o % C;
        float acc = 0.0f;
        #pragma unroll
        for (int k = 0; k < CR; k++) acc += h[s][k] * w2[k * C + j];
        gate[o] = 1.0f / (1.0f + expf(-acc));
    }
}

// ---------------- Kernel 3: out = x * gate[idx] (exact R1 version) -----------
__global__ __launch_bounds__(256) void k_mod(
    const float* __restrict__ x, const int* __restrict__ idx,
    const float* __restrict__ gate, float* __restrict__ out, int nrows)
{
    const int l    = threadIdx.x & 63;
    const int wrow = threadIdx.x >> 6;
    const float4* __restrict__ x4 = reinterpret_cast<const float4*>(x);
    const float4* __restrict__ g4 = reinterpret_cast<const float4*>(gate);
    float4* __restrict__ o4 = reinterpret_cast<float4*>(out);

    for (int row = blockIdx.x * 4 + wrow; row < nrows; row += gridDim.x * 4) {
        const int s = idx[row];                  // wave-uniform -> broadcast
        float4 v = x4[row * (C / 4) + l];
        const float4 g = g4[s * (C / 4) + l];    // 16 KB table, L1/L2-resident
        v.x *= g.x; v.y *= g.y; v.z *= g.z; v.w *= g.w;
        o4[row * (C / 4) + l] = v;
    }
}

extern "C" void kernel_launch(void* const* d_in, const int* in_sizes, int n_in,
                              void* d_out, int out_size, void* d_ws, size_t ws_size,
                              hipStream_t stream)
{
    const float* x   = (const float*)d_in[0];
    const int*   idx = (const int*)  d_in[1];
    const float* w1  = (const float*)d_in[2];
    const float* w2  = (const float*)d_in[3];
    float* out = (float*)d_out;
    const int nrows = in_sizes[1];

    // ws: [psum: NREP*S*C f32][pcnt: S i32][cursor: S i32][gate: S*C f32][perm: nrows i32]
    float* psum   = (float*)d_ws;
    int*   pcnt   = (int*)(psum + NREP * S * C);
    int*   cursor = pcnt + S;
    float* gate   = (float*)(cursor + S);
    int*   perm   = (int*)(gate + S * C);

    const size_t zero_bytes = NREP * S * C * sizeof(float) + 2 * S * sizeof(int);
    (void)hipMemsetAsync(d_ws, 0, zero_bytes, stream);

    k_hist   <<< 128, 256, 0, stream>>>(idx, pcnt, nrows);
    k_scatter<<< 512, 256, 0, stream>>>(idx, pcnt, cursor, perm, nrows);
    k_segsum <<<1024, 256, 0, stream>>>(x, perm, pcnt, psum, nrows);
    k_mlp    <<<   1, 256, 0, stream>>>(psum, pcnt, w1, w2, gate);
    k_mod    <<<2048, 256, 0, stream>>>(x, idx, gate, out, nrows);
}

// Round 11
// 853.554 us; speedup vs baseline: 1.0836x; 1.0836x over previous
//
#include <hip/hip_runtime.h>
#include <math.h>

#define C 256
#define S 16
#define CR 64
#define NREP 16        // psum replicas (atomic contention /16)

typedef float f4 __attribute__((ext_vector_type(4)));

// ---------------- Kernel 1: segment sums + counts, wave-specialized ----------
// Wave w of each block OWNS segments [4w, 4w+4). Per 64-row superblock:
// one coalesced idx load (L1-broadcast to all 4 waves); ballot gives each
// wave its private row mask; scalar ffs bit-walk extracts 4 rows/iter ->
// 4 independent 1KB loads in flight -> 16 fmac/row TOTAL chip-wide
// (4-way predicate on the owning wave only; other waves never touch the row).
// Each row read exactly once; reads stay inside a 64KB window.
__global__ __launch_bounds__(256, 4) void k_segsum(
    const float* __restrict__ x, const int* __restrict__ idx,
    float* __restrict__ psum, int* __restrict__ pcnt, int nrows)
{
    const int lane = threadIdx.x & 63;
    const int w    = threadIdx.x >> 6;          // wave = segment group owner
    const int blk  = blockIdx.x;
    const int nblk = gridDim.x;

    f4 a0={0,0,0,0}, a1={0,0,0,0}, a2={0,0,0,0}, a3={0,0,0,0};
    int c0=0, c1=0, c2=0, c3=0;                 // counts for my 4 segments

    const f4* __restrict__ x4 = reinterpret_cast<const f4*>(x);
    const int nsb = (nrows + 63) >> 6;          // superblocks (ceil)
    const int base = w << 2;                    // my first segment

    // add row value vv (scaled by scalar validity hv) into my 4 accumulators
    #define ROW4(sv, hv, vv) { \
        const float m0 = (sv == base + 0) ? hv : 0.0f; \
        const float m1 = (sv == base + 1) ? hv : 0.0f; \
        const float m2 = (sv == base + 2) ? hv : 0.0f; \
        const float m3 = (sv == base + 3) ? hv : 0.0f; \
        a0.x = fmaf(m0, vv.x, a0.x); a0.y = fmaf(m0, vv.y, a0.y); \
        a0.z = fmaf(m0, vv.z, a0.z); a0.w = fmaf(m0, vv.w, a0.w); \
        a1.x = fmaf(m1, vv.x, a1.x); a1.y = fmaf(m1, vv.y, a1.y); \
        a1.z = fmaf(m1, vv.z, a1.z); a1.w = fmaf(m1, vv.w, a1.w); \
        a2.x = fmaf(m2, vv.x, a2.x); a2.y = fmaf(m2, vv.y, a2.y); \
        a2.z = fmaf(m2, vv.z, a2.z); a2.w = fmaf(m2, vv.w, a2.w); \
        a3.x = fmaf(m3, vv.x, a3.x); a3.y = fmaf(m3, vv.y, a3.y); \
        a3.z = fmaf(m3, vv.z, a3.z); a3.w = fmaf(m3, vv.w, a3.w); }

    for (int sb = blk; sb < nsb; sb += nblk) {
        const int row0 = sb << 6;
        const bool valid = (row0 + lane) < nrows;
        const int myseg = valid ? idx[row0 + lane] : -1;   // 256B, L1-shared
        unsigned long long m = __ballot((myseg >> 2) == w);

        c0 += (int)__popcll(__ballot(myseg == base + 0));
        c1 += (int)__popcll(__ballot(myseg == base + 1));
        c2 += (int)__popcll(__ballot(myseg == base + 2));
        c3 += (int)__popcll(__ballot(myseg == base + 3));

        while (m) {
            // extract up to 4 set bits (scalar); duplicates neutralized by hK=0
            const int  b0 = (int)__ffsll((long long)m) - 1;  m &= m - 1;
            const bool h1 = m != 0;
            const int  b1 = h1 ? (int)__ffsll((long long)m) - 1 : b0;
            if (h1) m &= m - 1;
            const bool h2 = m != 0;
            const int  b2 = h2 ? (int)__ffsll((long long)m) - 1 : b0;
            if (h2) m &= m - 1;
            const bool h3 = m != 0;
            const int  b3 = h3 ? (int)__ffsll((long long)m) - 1 : b0;
            if (h3) m &= m - 1;

            // 4 independent 1KB row loads in flight (SGPR base + lane)
            const f4 v0 = x4[(size_t)(row0 + b0) * (C/4) + lane];
            const f4 v1 = x4[(size_t)(row0 + b1) * (C/4) + lane];
            const f4 v2 = x4[(size_t)(row0 + b2) * (C/4) + lane];
            const f4 v3 = x4[(size_t)(row0 + b3) * (C/4) + lane];

            const int s0 = __builtin_amdgcn_readlane(myseg, b0);
            const int s1 = __builtin_amdgcn_readlane(myseg, b1);
            const int s2 = __builtin_amdgcn_readlane(myseg, b2);
            const int s3 = __builtin_amdgcn_readlane(myseg, b3);

            ROW4(s0, 1.0f, v0)
            ROW4(s1, h1 ? 1.0f : 0.0f, v1)
            ROW4(s2, h2 ? 1.0f : 0.0f, v2)
            ROW4(s3, h3 ? 1.0f : 0.0f, v3)
        }
    }
    #undef ROW4

    // flush: waves own disjoint segments -> direct atomics, no LDS
    const int rep = ((blk << 2) | w) & (NREP - 1);
    float* gs = psum + (size_t)rep * S * C;
    #define FLUSH(K) { float* fp = gs + (base + K) * C + 4 * lane; \
        atomicAdd(fp + 0, a##K.x); atomicAdd(fp + 1, a##K.y); \
        atomicAdd(fp + 2, a##K.z); atomicAdd(fp + 3, a##K.w); \
        if (lane == 0 && c##K) atomicAdd(&pcnt[base + K], c##K); }
    FLUSH(0) FLUSH(1) FLUSH(2) FLUSH(3)
    #undef FLUSH
}

// ---------------- Kernel 2: reduce replicas + tiny SE MLP ----------------
__global__ __launch_bounds__(256) void k_mlp(
    const float* __restrict__ psum, const int* __restrict__ pcnt,
    const float* __restrict__ w1, const float* __restrict__ w2,
    float* __restrict__ gate)
{
    __shared__ float sm[S][C];
    __shared__ float h[S][CR];
    __shared__ float cnt[S];
    const int t = threadIdx.x;

    if (t < S) cnt[t] = fmaxf((float)pcnt[t], 1.0f);
    __syncthreads();

    for (int i = t; i < S * C; i += 256) {
        float v = 0.0f;
        #pragma unroll
        for (int r = 0; r < NREP; r++) v += psum[r * S * C + i];
        sm[i / C][i % C] = v / cnt[i / C];
    }
    __syncthreads();

    for (int o = t; o < S * CR; o += 256) {
        const int s = o / CR, j = o % CR;
        float acc = 0.0f;
        #pragma unroll 4
        for (int k = 0; k < C; k++) acc += sm[s][k] * w1[k * CR + j];
        h[s][j] = fmaxf(acc, 0.0f);
    }
    __syncthreads();

    for (int o = t; o < S * C; o += 256) {
        const int s = o / C, j = o % C;
        float acc = 0.0f;
        #pragma unroll
        for (int k = 0; k < CR; k++) acc += h[s][k] * w2[k * C + j];
        gate[o] = 1.0f / (1.0f + expf(-acc));
    }
}

// ---------------- Kernel 3: out = x * gate[idx] (exact R1 version) -----------
__global__ __launch_bounds__(256) void k_mod(
    const float* __restrict__ x, const int* __restrict__ idx,
    const float* __restrict__ gate, float* __restrict__ out, int nrows)
{
    const int l    = threadIdx.x & 63;
    const int wrow = threadIdx.x >> 6;
    const float4* __restrict__ x4 = reinterpret_cast<const float4*>(x);
    const float4* __restrict__ g4 = reinterpret_cast<const float4*>(gate);
    float4* __restrict__ o4 = reinterpret_cast<float4*>(out);

    for (int row = blockIdx.x * 4 + wrow; row < nrows; row += gridDim.x * 4) {
        const int s = idx[row];                  // wave-uniform -> broadcast
        float4 v = x4[row * (C / 4) + l];
        const float4 g = g4[s * (C / 4) + l];    // 16 KB table, L1/L2-resident
        v.x *= g.x; v.y *= g.y; v.z *= g.z; v.w *= g.w;
        o4[row * (C / 4) + l] = v;
    }
}

extern "C" void kernel_launch(void* const* d_in, const int* in_sizes, int n_in,
                              void* d_out, int out_size, void* d_ws, size_t ws_size,
                              hipStream_t stream)
{
    const float* x   = (const float*)d_in[0];
    const int*   idx = (const int*)  d_in[1];
    const float* w1  = (const float*)d_in[2];
    const float* w2  = (const float*)d_in[3];
    float* out = (float*)d_out;
    const int nrows = in_sizes[1];

    // ws: [psum: NREP*S*C f32][pcnt: S i32][gate: S*C f32]
    float* psum = (float*)d_ws;
    int*   pcnt = (int*)(psum + NREP * S * C);
    float* gate = (float*)(pcnt + S);

    const size_t zero_bytes = NREP * S * C * sizeof(float) + S * sizeof(int);
    (void)hipMemsetAsync(d_ws, 0, zero_bytes, stream);

    k_segsum<<<1024, 256, 0, stream>>>(x, idx, psum, pcnt, nrows);
    k_mlp   <<<   1, 256, 0, stream>>>(psum, pcnt, w1, w2, gate);
    k_mod   <<<2048, 256, 0, stream>>>(x, idx, gate, out, nrows);
}

// Round 12
// 811.996 us; speedup vs baseline: 1.1390x; 1.0512x over previous
//
#include <hip/hip_runtime.h>
#include <math.h>

#define C 256
#define S 16
#define CR 64
#define NREP 16        // psum replicas (atomic contention /16)

typedef float f2 __attribute__((ext_vector_type(2)));
typedef float f4 __attribute__((ext_vector_type(4)));

// ---------------- Kernel 0: histogram of idx (counts per segment) ------------
__global__ __launch_bounds__(256) void k_hist(
    const int* __restrict__ idx, int* __restrict__ pcnt, int nrows)
{
    const int lane = threadIdx.x & 63;
    const int tid  = blockIdx.x * blockDim.x + threadIdx.x;
    const int T    = gridDim.x * blockDim.x;
    const int padded = ((nrows + 63) >> 6) << 6;

    int c0=0,c1=0,c2=0,c3=0,c4=0,c5=0,c6=0,c7=0,
        c8=0,c9=0,c10=0,c11=0,c12=0,c13=0,c14=0,c15=0;

    for (int i = tid; i < padded; i += T) {
        const int v = (i < nrows) ? idx[i] : -1;
        #define CNT(K) c##K += (int)__popcll(__ballot(v == K));
        CNT(0)  CNT(1)  CNT(2)  CNT(3)  CNT(4)  CNT(5)  CNT(6)  CNT(7)
        CNT(8)  CNT(9)  CNT(10) CNT(11) CNT(12) CNT(13) CNT(14) CNT(15)
        #undef CNT
    }
    if (lane == 0) {
        #define FL(K) if (c##K) atomicAdd(&pcnt[K], c##K);
        FL(0)  FL(1)  FL(2)  FL(3)  FL(4)  FL(5)  FL(6)  FL(7)
        FL(8)  FL(9)  FL(10) FL(11) FL(12) FL(13) FL(14) FL(15)
        #undef FL
    }
}

// ---------------- Kernel 1: segment sums, HALF-ROW predicated FMAC -----------
// Key change vs R5: per-thread state halved (float2 accumulators) to get
// VGPR <= 64 -> 8 waves/SIMD (occupancy quantizes at 64/128/256 VGPR).
// Block = 64-row superblock. Waves (0,1) = rows 0..31 x halves (0,1);
// waves (2,3) = rows 32..63. One coalesced idx line, L1-broadcast; scalar
// readlane masks -> predicated fmac (no branches, no LDS in hot loop).
__global__ __launch_bounds__(256, 8) void k_segsum(
    const float* __restrict__ x, const int* __restrict__ idx,
    float* __restrict__ psum, int nrows)
{
    const int lane = threadIdx.x & 63;
    const int w    = threadIdx.x >> 6;
    const int half = w & 1;                     // 128-channel half
    const int span = (w >> 1) << 5;             // row offset: 0 or 32

    f2 a0={0,0},a1={0,0},a2={0,0},a3={0,0},a4={0,0},a5={0,0},a6={0,0},a7={0,0},
       a8={0,0},a9={0,0},a10={0,0},a11={0,0},a12={0,0},a13={0,0},a14={0,0},a15={0,0};

    const f2* __restrict__ x2 = reinterpret_cast<const f2*>(x);  // 128 f2/row

    #define ACC1(K, sv, vv) { const float m = (sv == K) ? 1.0f : 0.0f; \
        a##K.x = fmaf(m, vv.x, a##K.x); a##K.y = fmaf(m, vv.y, a##K.y); }
    #define ROW(sv, vv) \
        ACC1(0,sv,vv)  ACC1(1,sv,vv)  ACC1(2,sv,vv)  ACC1(3,sv,vv) \
        ACC1(4,sv,vv)  ACC1(5,sv,vv)  ACC1(6,sv,vv)  ACC1(7,sv,vv) \
        ACC1(8,sv,vv)  ACC1(9,sv,vv)  ACC1(10,sv,vv) ACC1(11,sv,vv) \
        ACC1(12,sv,vv) ACC1(13,sv,vv) ACC1(14,sv,vv) ACC1(15,sv,vv)

    const int nsb = nrows >> 6;
    for (int sb = blockIdx.x; sb < nsb; sb += gridDim.x) {
        const int row0 = sb << 6;
        const int vidx = idx[row0 + lane];       // 256 B, shared by 4 waves
        const f2* __restrict__ p =
            x2 + (size_t)(row0 + span) * 128 + half * 64 + lane;
        #pragma unroll 1
        for (int j = 0; j < 32; j += 8) {
            f2  v[8];
            int s[8];
            #pragma unroll
            for (int k = 0; k < 8; k++)          // 8 independent 512B wave-loads
                v[k] = p[(size_t)(j + k) * 128];
            #pragma unroll
            for (int k = 0; k < 8; k++)
                s[k] = __builtin_amdgcn_readlane(vidx, span + j + k);
            #pragma unroll
            for (int k = 0; k < 8; k++) { ROW(s[k], v[k]) }
        }
    }
    if (blockIdx.x == 0 && span == 0) {          // tail (none when %64==0)
        for (int r = nsb << 6; r < nrows; ++r) {
            const int sv = __builtin_amdgcn_readfirstlane(idx[r]);
            const f2 vv = x2[(size_t)r * 128 + half * 64 + lane];
            ROW(sv, vv)
        }
    }
    #undef ROW
    #undef ACC1

    // flush: 16 KB LDS (keeps 8 blocks/CU), two 8-segment chunks
    __shared__ float red[2][8][C];
    const int rg   = w >> 1;                     // row-group 0/1
    const int coff = half * 128 + 2 * lane;      // my channel pair
    const int t    = threadIdx.x;                // reducer: channel t
    const int rep  = (blockIdx.x * 4 + w) & (NREP - 1);
    float* gs = psum + (size_t)rep * S * C;

    #define ST(K, SL) *reinterpret_cast<f2*>(&red[rg][SL][coff]) = a##K;
    ST(0,0) ST(1,1) ST(2,2) ST(3,3) ST(4,4) ST(5,5) ST(6,6) ST(7,7)
    __syncthreads();
    #pragma unroll
    for (int s_ = 0; s_ < 8; s_++) {
        const float v = red[0][s_][t] + red[1][s_][t];
        atomicAdd(&gs[s_ * C + t], v);
    }
    __syncthreads();
    ST(8,0) ST(9,1) ST(10,2) ST(11,3) ST(12,4) ST(13,5) ST(14,6) ST(15,7)
    __syncthreads();
    #pragma unroll
    for (int s_ = 0; s_ < 8; s_++) {
        const float v = red[0][s_][t] + red[1][s_][t];
        atomicAdd(&gs[(8 + s_) * C + t], v);
    }
    #undef ST
}

// ---------------- Kernel 2: reduce replicas + tiny SE MLP ----------------
__global__ __launch_bounds__(256) void k_mlp(
    const float* __restrict__ psum, const int* __restrict__ pcnt,
    const float* __restrict__ w1, const float* __restrict__ w2,
    float* __restrict__ gate)
{
    __shared__ float sm[S][C];
    __shared__ float h[S][CR];
    __shared__ float cnt[S];
    const int t = threadIdx.x;

    if (t < S) cnt[t] = fmaxf((float)pcnt[t], 1.0f);
    __syncthreads();

    for (int i = t; i < S * C; i += 256) {
        float v = 0.0f;
        #pragma unroll
        for (int r = 0; r < NREP; r++) v += psum[r * S * C + i];
        sm[i / C][i % C] = v / cnt[i / C];
    }
    __syncthreads();

    for (int o = t; o < S * CR; o += 256) {
        const int s = o / CR, j = o % CR;
        float acc = 0.0f;
        #pragma unroll 4
        for (int k = 0; k < C; k++) acc += sm[s][k] * w1[k * CR + j];
        h[s][j] = fmaxf(acc, 0.0f);
    }
    __syncthreads();

    for (int o = t; o < S * C; o += 256) {
        const int s = o / C, j = o % C;
        float acc = 0.0f;
        #pragma unroll
        for (int k = 0; k < CR; k++) acc += h[s][k] * w2[k * C + j];
        gate[o] = 1.0f / (1.0f + expf(-acc));
    }
}

// ---------------- Kernel 3: out = x * gate[idx] (exact R1 version) -----------
__global__ __launch_bounds__(256) void k_mod(
    const float* __restrict__ x, const int* __restrict__ idx,
    const float* __restrict__ gate, float* __restrict__ out, int nrows)
{
    const int l    = threadIdx.x & 63;
    const int wrow = threadIdx.x >> 6;
    const float4* __restrict__ x4 = reinterpret_cast<const float4*>(x);
    const float4* __restrict__ g4 = reinterpret_cast<const float4*>(gate);
    float4* __restrict__ o4 = reinterpret_cast<float4*>(out);

    for (int row = blockIdx.x * 4 + wrow; row < nrows; row += gridDim.x * 4) {
        const int s = idx[row];                  // wave-uniform -> broadcast
        float4 v = x4[row * (C / 4) + l];
        const float4 g = g4[s * (C / 4) + l];    // 16 KB table, L1/L2-resident
        v.x *= g.x; v.y *= g.y; v.z *= g.z; v.w *= g.w;
        o4[row * (C / 4) + l] = v;
    }
}

extern "C" void kernel_launch(void* const* d_in, const int* in_sizes, int n_in,
                              void* d_out, int out_size, void* d_ws, size_t ws_size,
                              hipStream_t stream)
{
    const float* x   = (const float*)d_in[0];
    const int*   idx = (const int*)  d_in[1];
    const float* w1  = (const float*)d_in[2];
    const float* w2  = (const float*)d_in[3];
    float* out = (float*)d_out;
    const int nrows = in_sizes[1];

    // ws: [psum: NREP*S*C f32][pcnt: S i32][gate: S*C f32]
    float* psum = (float*)d_ws;
    int*   pcnt = (int*)(psum + NREP * S * C);
    float* gate = (float*)(pcnt + S);

    const size_t zero_bytes = NREP * S * C * sizeof(float) + S * sizeof(int);
    (void)hipMemsetAsync(d_ws, 0, zero_bytes, stream);

    k_hist  <<< 128, 256, 0, stream>>>(idx, pcnt, nrows);
    k_segsum<<<4096, 256, 0, stream>>>(x, idx, psum, nrows);
    k_mlp   <<<   1, 256, 0, stream>>>(psum, pcnt, w1, w2, gate);
    k_mod   <<<2048, 256, 0, stream>>>(x, idx, gate, out, nrows);
}

// Round 13
// 777.449 us; speedup vs baseline: 1.1896x; 1.0444x over previous
//
#include <hip/hip_runtime.h>
#include <math.h>

#define C 256
#define S 16
#define CR 64

typedef float f4 __attribute__((ext_vector_type(4)));

// ---------------- Kernel 0: histogram of idx (counts per segment) ------------
__global__ __launch_bounds__(256) void k_hist(
    const int* __restrict__ idx, int* __restrict__ pcnt, int nrows)
{
    const int lane = threadIdx.x & 63;
    const int tid  = blockIdx.x * blockDim.x + threadIdx.x;
    const int T    = gridDim.x * blockDim.x;
    const int padded = ((nrows + 63) >> 6) << 6;

    int c0=0,c1=0,c2=0,c3=0,c4=0,c5=0,c6=0,c7=0,
        c8=0,c9=0,c10=0,c11=0,c12=0,c13=0,c14=0,c15=0;

    for (int i = tid; i < padded; i += T) {
        const int v = (i < nrows) ? idx[i] : -1;
        #define CNT(K) c##K += (int)__popcll(__ballot(v == K));
        CNT(0)  CNT(1)  CNT(2)  CNT(3)  CNT(4)  CNT(5)  CNT(6)  CNT(7)
        CNT(8)  CNT(9)  CNT(10) CNT(11) CNT(12) CNT(13) CNT(14) CNT(15)
        #undef CNT
    }
    if (lane == 0) {
        #define FL(K) if (c##K) atomicAdd(&pcnt[K], c##K);
        FL(0)  FL(1)  FL(2)  FL(3)  FL(4)  FL(5)  FL(6)  FL(7)
        FL(8)  FL(9)  FL(10) FL(11) FL(12) FL(13) FL(14) FL(15)
        #undef FL
    }
}

// ---------------- Kernel 1: segment sums, predicated FMAC, atomic-free -------
// R5 structure (best measured) with the flush de-atomized: block-level LDS
// reduction then PLAIN stores into a private parts[blk][S][C] slot.
// Kernel-boundary release makes parts coherent for k_mlp (no atomics, no
// ~134MB atomic write-through). Plain cached x loads (keep tail in L3 for
// the reverse-order k_mod).
__global__ __launch_bounds__(256, 4) void k_segsum(
    const float* __restrict__ x, const int* __restrict__ idx,
    float* __restrict__ parts, int nrows)
{
    const int lane = threadIdx.x & 63;
    const int w    = threadIdx.x >> 6;

    f4 a0={0,0,0,0},a1={0,0,0,0},a2={0,0,0,0},a3={0,0,0,0},
       a4={0,0,0,0},a5={0,0,0,0},a6={0,0,0,0},a7={0,0,0,0},
       a8={0,0,0,0},a9={0,0,0,0},a10={0,0,0,0},a11={0,0,0,0},
       a12={0,0,0,0},a13={0,0,0,0},a14={0,0,0,0},a15={0,0,0,0};

    const f4* __restrict__ x4 = reinterpret_cast<const f4*>(x);

    #define ACC1(K, sv, vv) { const float m = (sv == K) ? 1.0f : 0.0f; \
        a##K.x = fmaf(m, vv.x, a##K.x); a##K.y = fmaf(m, vv.y, a##K.y); \
        a##K.z = fmaf(m, vv.z, a##K.z); a##K.w = fmaf(m, vv.w, a##K.w); }
    #define ROW(sv, vv) \
        ACC1(0,sv,vv)  ACC1(1,sv,vv)  ACC1(2,sv,vv)  ACC1(3,sv,vv) \
        ACC1(4,sv,vv)  ACC1(5,sv,vv)  ACC1(6,sv,vv)  ACC1(7,sv,vv) \
        ACC1(8,sv,vv)  ACC1(9,sv,vv)  ACC1(10,sv,vv) ACC1(11,sv,vv) \
        ACC1(12,sv,vv) ACC1(13,sv,vv) ACC1(14,sv,vv) ACC1(15,sv,vv)

    const int nsb = nrows >> 6;                  // 64-row superblocks
    // wave w handles quarter w of each superblock: rows 16w..16w+15
    for (int sb = blockIdx.x; sb < nsb; sb += gridDim.x) {
        const int row0 = sb << 6;
        const int vidx = idx[row0 + lane];       // 256 B line, L1-shared x4 waves
        const f4* __restrict__ p = x4 + (size_t)(row0 + (w << 4)) * (C/4) + lane;
        #pragma unroll 1
        for (int j = 0; j < 16; j += 8) {
            f4  v[8];
            int s[8];
            #pragma unroll
            for (int k = 0; k < 8; k++)          // 8 KB/wave in flight
                v[k] = p[(size_t)(j + k) * (C/4)];
            #pragma unroll
            for (int k = 0; k < 8; k++)
                s[k] = __builtin_amdgcn_readlane(vidx, (w << 4) + j + k);
            #pragma unroll
            for (int k = 0; k < 8; k++) { ROW(s[k], v[k]) }
        }
    }
    if (blockIdx.x == 0 && w == 0) {             // tail (none when %64==0)
        for (int r = nsb << 6; r < nrows; ++r) {
            const int sv = __builtin_amdgcn_readfirstlane(idx[r]);
            const f4 vv = x4[(size_t)r * (C/4) + lane];
            ROW(sv, vv)
        }
    }
    #undef ROW
    #undef ACC1

    // flush: 32 KB LDS, two 8-segment chunks -> PLAIN stores to private slot
    __shared__ float red[4][8][C];
    const int t = threadIdx.x;
    float* slot = parts + (size_t)blockIdx.x * S * C;

    #define ST(K, SL) *reinterpret_cast<f4*>(&red[w][SL][4 * lane]) = a##K;
    ST(0,0) ST(1,1) ST(2,2) ST(3,3) ST(4,4) ST(5,5) ST(6,6) ST(7,7)
    __syncthreads();
    #pragma unroll
    for (int s_ = 0; s_ < 8; s_++)
        slot[s_ * C + t] = red[0][s_][t] + red[1][s_][t] +
                           red[2][s_][t] + red[3][s_][t];
    __syncthreads();
    ST(8,0) ST(9,1) ST(10,2) ST(11,3) ST(12,4) ST(13,5) ST(14,6) ST(15,7)
    __syncthreads();
    #pragma unroll
    for (int s_ = 0; s_ < 8; s_++)
        slot[(8 + s_) * C + t] = red[0][s_][t] + red[1][s_][t] +
                                 red[2][s_][t] + red[3][s_][t];
    #undef ST
}

// ---------------- Kernel 2: per-segment reduce + SE MLP row ------------------
// Block b owns segment b: reduces parts[:, b, :] (coalesced 1KB/iter),
// then computes its own gate row. Fully parallel, no atomics.
__global__ __launch_bounds__(256) void k_mlp(
    const float* __restrict__ parts, const int* __restrict__ pcnt,
    const float* __restrict__ w1, const float* __restrict__ w2,
    float* __restrict__ gate, int nparts)
{
    __shared__ float sm[C];
    __shared__ float h[CR];
    const int b = blockIdx.x;
    const int t = threadIdx.x;

    // reduce partials for channel t (4-way ILP partial sums)
    float r0 = 0, r1 = 0, r2 = 0, r3 = 0;
    int p = 0;
    for (; p + 4 <= nparts; p += 4) {
        r0 += parts[(size_t)(p+0) * S * C + b * C + t];
        r1 += parts[(size_t)(p+1) * S * C + b * C + t];
        r2 += parts[(size_t)(p+2) * S * C + b * C + t];
        r3 += parts[(size_t)(p+3) * S * C + b * C + t];
    }
    for (; p < nparts; p++) r0 += parts[(size_t)p * S * C + b * C + t];
    const float cnt = fmaxf((float)pcnt[b], 1.0f);
    sm[t] = ((r0 + r1) + (r2 + r3)) / cnt;
    __syncthreads();

    if (t < CR) {                                // h = relu(sm @ w1)
        float acc = 0.0f;
        #pragma unroll 4
        for (int k = 0; k < C; k++) acc += sm[k] * w1[k * CR + t];
        h[t] = fmaxf(acc, 0.0f);
    }
    __syncthreads();

    float acc = 0.0f;                            // gate = sigmoid(h @ w2)
    #pragma unroll
    for (int k = 0; k < CR; k++) acc += h[k] * w2[k * C + t];
    gate[b * C + t] = 1.0f / (1.0f + expf(-acc));
}

// ---------------- Kernel 3: out = x * gate[idx], REVERSE order ---------------
// Tail-first: x's tail is still L3-resident from k_segsum -> free hits for
// the first ~256MB. out stored nontemporal so the 1GB write stream doesn't
// evict x from L3.
__global__ __launch_bounds__(256) void k_mod(
    const float* __restrict__ x, const int* __restrict__ idx,
    const float* __restrict__ gate, float* __restrict__ out, int nrows)
{
    const int l    = threadIdx.x & 63;
    const int wrow = threadIdx.x >> 6;
    const f4* __restrict__ x4 = reinterpret_cast<const f4*>(x);
    const f4* __restrict__ g4 = reinterpret_cast<const f4*>(gate);
    f4* __restrict__ o4 = reinterpret_cast<f4*>(out);

    for (int r = blockIdx.x * 4 + wrow; r < nrows; r += gridDim.x * 4) {
        const int row = nrows - 1 - r;           // reverse: tail first
        const int s = idx[row];                  // wave-uniform -> broadcast
        f4 v = x4[(size_t)row * (C/4) + l];
        const f4 g = g4[s * (C/4) + l];          // 16 KB table, L1-resident
        v *= g;
        __builtin_nontemporal_store(v, &o4[(size_t)row * (C/4) + l]);
    }
}

extern "C" void kernel_launch(void* const* d_in, const int* in_sizes, int n_in,
                              void* d_out, int out_size, void* d_ws, size_t ws_size,
                              hipStream_t stream)
{
    const float* x   = (const float*)d_in[0];
    const int*   idx = (const int*)  d_in[1];
    const float* w1  = (const float*)d_in[2];
    const float* w2  = (const float*)d_in[3];
    float* out = (float*)d_out;
    const int nrows = in_sizes[1];

    // segsum grid sized to fit parts in ws: [parts: sgrid*S*C f32][pcnt][gate]
    const size_t fixed = S * sizeof(int) + S * C * sizeof(float);
    int sgrid = 1024;
    if (ws_size < (size_t)sgrid * S * C * sizeof(float) + fixed) sgrid = 256;

    float* parts = (float*)d_ws;
    int*   pcnt  = (int*)(parts + (size_t)sgrid * S * C);
    float* gate  = (float*)(pcnt + S);

    (void)hipMemsetAsync(pcnt, 0, S * sizeof(int), stream);

    k_hist  <<<  128, 256, 0, stream>>>(idx, pcnt, nrows);
    k_segsum<<<sgrid, 256, 0, stream>>>(x, idx, parts, nrows);
    k_mlp   <<<    S, 256, 0, stream>>>(parts, pcnt, w1, w2, gate, sgrid);
    k_mod   <<< 2048, 256, 0, stream>>>(x, idx, gate, out, nrows);
}